// Round 6
// baseline (673.521 us; speedup 1.0000x reference)
//
#include <hip/hip_runtime.h>
#include <hip/hip_bf16.h>
#include <hip/hip_fp16.h>
#include <math.h>

#define NEG_SLOPE 0.2f

typedef unsigned int uint;
typedef __bf16 bf16x8 __attribute__((ext_vector_type(8)));
typedef __bf16 bf16x4 __attribute__((ext_vector_type(4)));
typedef __bf16 bf16x2 __attribute__((ext_vector_type(2)));
typedef _Float16 f16x2 __attribute__((ext_vector_type(2)));
typedef float floatx4 __attribute__((ext_vector_type(4)));

__device__ inline float2 h2_to_f2(uint v) {
    f16x2 p = __builtin_bit_cast(f16x2, v);
    return make_float2((float)p[0], (float)p[1]);
}

// ============================ CSR build =================================

__global__ void count_deg(const int* __restrict__ dst, int* __restrict__ deg, int E) {
    int i = blockIdx.x * blockDim.x + threadIdx.x;
    if (i < E) atomicAdd(&deg[dst[i]], 1);
}

__global__ void scan_block_k(const int* __restrict__ deg, int* __restrict__ off,
                             int* __restrict__ bsum, int N) {
    __shared__ int sdata[256];
    int t = threadIdx.x;
    int base = blockIdx.x * 1024 + t * 4;
    int v0 = (base + 0 < N) ? deg[base + 0] : 0;
    int v1 = (base + 1 < N) ? deg[base + 1] : 0;
    int v2 = (base + 2 < N) ? deg[base + 2] : 0;
    int v3 = (base + 3 < N) ? deg[base + 3] : 0;
    int s = v0 + v1 + v2 + v3;
    sdata[t] = s;
    __syncthreads();
    for (int d = 1; d < 256; d <<= 1) {
        int x = (t >= d) ? sdata[t - d] : 0;
        __syncthreads();
        sdata[t] += x;
        __syncthreads();
    }
    int run = sdata[t] - s;  // exclusive prefix within block
    if (t == 255) bsum[blockIdx.x] = sdata[255];
    if (base + 0 < N) off[base + 0] = run; run += v0;
    if (base + 1 < N) off[base + 1] = run; run += v1;
    if (base + 2 < N) off[base + 2] = run; run += v2;
    if (base + 3 < N) off[base + 3] = run;
}

__global__ void scan_bsum_k(int* bsum, int G) {
    __shared__ int sdata[1024];
    int t = threadIdx.x;
    int v = (t < G) ? bsum[t] : 0;
    sdata[t] = v;
    __syncthreads();
    for (int d = 1; d < 1024; d <<= 1) {
        int x = (t >= d) ? sdata[t - d] : 0;
        __syncthreads();
        sdata[t] += x;
        __syncthreads();
    }
    if (t < G) bsum[t] = sdata[t] - v;  // exclusive
}

__global__ void add_bsum_k(int* __restrict__ off, const int* __restrict__ bsum,
                           int N, int Etot) {
    int i = blockIdx.x * blockDim.x + threadIdx.x;
    if (i < N) off[i] += bsum[i >> 10];
    else if (i == N) off[N] = Etot;
}

__global__ void copy_off_k(const int* __restrict__ off, int* __restrict__ cursor, int N) {
    int i = blockIdx.x * blockDim.x + threadIdx.x;
    if (i < N) cursor[i] = off[i];
}

// CSR scatter. The entry store is an atomicExch, NOT a plain store: device-scope
// atomics execute at the coherent memory-side point, so the random 4B writes to
// a 64B line merge in one cache instead of leaving partial-dirty copies in 8
// non-coherent XCD L2s (plain-store version measured 107MB WRITE_SIZE for 6.4MB
// of payload, 120us; this drops it to ~payload).
__global__ void fill_csr(const int* __restrict__ src, const int* __restrict__ dst,
                         int* __restrict__ cursor, int* __restrict__ csr_src, int E) {
    int i = blockIdx.x * blockDim.x + threadIdx.x;
    if (i < E) {
        int p = atomicAdd(&cursor[dst[i]], 1);
        atomicExch(&csr_src[p], src[i]);
    }
}

// ===================== splits (fp32 -> hi/lo bf16) =======================

__global__ void split_x_k(const float* __restrict__ in, __bf16* __restrict__ hi,
                          __bf16* __restrict__ lo, int n4) {
    int i = blockIdx.x * blockDim.x + threadIdx.x;
    if (i >= n4) return;
    float4 v = ((const float4*)in)[i];
    bf16x4 h = { (__bf16)v.x, (__bf16)v.y, (__bf16)v.z, (__bf16)v.w };
    bf16x4 l = { (__bf16)(v.x - (float)h[0]), (__bf16)(v.y - (float)h[1]),
                 (__bf16)(v.z - (float)h[2]), (__bf16)(v.w - (float)h[3]) };
    ((bf16x4*)hi)[i] = h;
    ((bf16x4*)lo)[i] = l;
}

// split + fragment-order all three 128x128 W's.
// Wf element (ct,kt,q,n16,j) holds W[k][ncol] with k = kt*32+q*8+j,
// ncol = ct*16+n16. Flat: (((ct*4+kt)*64) + q*16 + n16)*8 + j
// -> a wave's B-frag load (fixed ct,kt; lane = q*16+n16) is contiguous 1 KB.
__global__ void split_w_k(const float* __restrict__ W0, const float* __restrict__ W1,
                          const float* __restrict__ W2, __bf16* __restrict__ Wfh,
                          __bf16* __restrict__ Wfl) {
    const float* W = (blockIdx.y == 0) ? W0 : (blockIdx.y == 1) ? W1 : W2;
    size_t base = (size_t)blockIdx.y * 16384;
    int i = blockIdx.x * 256 + threadIdx.x;   // 0..16383
    int k = i >> 7, ncol = i & 127;
    int ct = ncol >> 4, n16 = ncol & 15;
    int kt = k >> 5, q = (k & 31) >> 3, j = k & 7;
    size_t flat = (size_t)(((ct * 4 + kt) * 64) + q * 16 + n16) * 8 + j;
    float v = W[i];
    __bf16 h = (__bf16)v;
    __bf16 l = (__bf16)(v - (float)h);
    Wfh[base + flat] = h;
    Wfl[base + flat] = l;
}

// ================ split-bf16 MFMA GEMM + fused alphas ====================
// h = Ah*Wh + Ah*Wl + Al*Wh  (fp32-equivalent, rel err ~2^-18).
// 256 threads = 4 waves; wave = 16-row strip x 128 cols,
// 8 col-tiles x 4 k-steps x 3 MFMAs. A frags from global (row-major bf16,
// 64B/row contiguous per load); B frags from fragment-ordered W tables
// (contiguous 1KB per wave-load, L2-resident). Epilogue: alphas from fp32
// acc (shfl_xor over n-lanes); fp16 H via LDS.

__global__ __launch_bounds__(256, 2) void gemm_split(
    const __bf16* __restrict__ Ah, const __bf16* __restrict__ Al,
    const __bf16* __restrict__ Wh, const __bf16* __restrict__ Wl,
    const float* __restrict__ avs, const float* __restrict__ avd,
    _Float16* __restrict__ Hh, float* __restrict__ asrc, float* __restrict__ adst,
    int M) {
    __shared__ _Float16 hl[64][132];
    int tid = threadIdx.x;
    int wv = tid >> 6, lane = tid & 63;
    int n = lane & 15, q = lane >> 4;

    int arow_g = blockIdx.x * 64 + wv * 16 + n;
    int arow_c = (arow_g < M) ? arow_g : (M - 1);
    const bf16x8* ah = (const bf16x8*)(Ah + (size_t)arow_c * 128);
    const bf16x8* al = (const bf16x8*)(Al + (size_t)arow_c * 128);
    bf16x8 a_h[4], a_l[4];
    #pragma unroll
    for (int kt = 0; kt < 4; ++kt) {
        a_h[kt] = ah[kt * 4 + q];   // k = kt*32 + q*8 + j
        a_l[kt] = al[kt * 4 + q];
    }

    floatx4 acc[8];
    #pragma unroll
    for (int ct = 0; ct < 8; ++ct) {
        floatx4 c = {0.f, 0.f, 0.f, 0.f};
        #pragma unroll
        for (int kt = 0; kt < 4; ++kt) {
            size_t fo = (size_t)((ct * 4 + kt) * 64 + lane);
            bf16x8 bh = ((const bf16x8*)Wh)[fo];
            bf16x8 bl = ((const bf16x8*)Wl)[fo];
            c = __builtin_amdgcn_mfma_f32_16x16x32_bf16(a_h[kt], bh, c, 0, 0, 0);
            c = __builtin_amdgcn_mfma_f32_16x16x32_bf16(a_h[kt], bl, c, 0, 0, 0);
            c = __builtin_amdgcn_mfma_f32_16x16x32_bf16(a_l[kt], bh, c, 0, 0, 0);
        }
        acc[ct] = c;
    }

    // fused alphas. D layout: row = q*4+r, col = ct*16+n.
    float ps[4] = {0.f, 0.f, 0.f, 0.f}, pd[4] = {0.f, 0.f, 0.f, 0.f};
    #pragma unroll
    for (int ct = 0; ct < 8; ++ct) {
        float sv = avs[ct * 16 + n], dv = avd[ct * 16 + n];
        #pragma unroll
        for (int r = 0; r < 4; ++r) {
            ps[r] += acc[ct][r] * sv;
            pd[r] += acc[ct][r] * dv;
        }
    }
    #pragma unroll
    for (int m = 1; m < 16; m <<= 1) {
        #pragma unroll
        for (int r = 0; r < 4; ++r) {
            ps[r] += __shfl_xor(ps[r], m, 64);
            pd[r] += __shfl_xor(pd[r], m, 64);
        }
    }
    if (n == 0) {
        #pragma unroll
        for (int r = 0; r < 4; ++r) {
            int grow = blockIdx.x * 64 + wv * 16 + q * 4 + r;
            if (grow < M) { asrc[grow] = ps[r]; adst[grow] = pd[r]; }
        }
    }

    // fp16 H store via LDS (coalesced uint)
    #pragma unroll
    for (int ct = 0; ct < 8; ++ct)
        #pragma unroll
        for (int r = 0; r < 4; ++r)
            hl[wv * 16 + q * 4 + r][ct * 16 + n] = (_Float16)acc[ct][r];
    __syncthreads();

    int r0 = blockIdx.x * 64;
    for (int i = tid; i < 64 * 64; i += 256) {
        int rr = i >> 6, cu = i & 63;
        int gr = r0 + rr;
        if (gr < M)
            ((uint*)Hh)[(size_t)gr * 64 + cu] = *(const uint*)&hl[rr][cu * 2];
    }
}

// ========================= edge aggregation ==============================
// one wave per dst node; fp16 h rows (256 B, one uint/lane). Edges in masked
// chunks of 4 -> 4 independent gather chains in flight per wave.
// Softmax weights are fp32-exact (alphas from exact GEMM accumulators);
// only the averaged features carry fp16 noise (~2^-11, non-compounding).

template <int FINAL>
__global__ __launch_bounds__(256) void aggregate_k(
    const _Float16* __restrict__ h, const float* __restrict__ asrc,
    const float* __restrict__ adst, const int* __restrict__ off,
    const int* __restrict__ csr_src, const float* __restrict__ bias,
    float* __restrict__ out_f, __bf16* __restrict__ a_hi, __bf16* __restrict__ a_lo,
    int N, int E) {
    int gid = blockIdx.x * blockDim.x + threadIdx.x;
    int wid = gid >> 6, lane = gid & 63;
    if (wid >= N) return;
    const uint* hrows = (const uint*)h;   // 64 uints (128 fp16) per row
    float ad = adst[wid];
    float acc0, acc1, denom;

    {   // self loop
        float e = asrc[wid] + ad;
        e = (e > 0.f) ? e : NEG_SLOPE * e;
        float w = __expf(e);
        float2 f = h2_to_f2(hrows[(size_t)wid * 64 + lane]);
        denom = w; acc0 = w * f.x; acc1 = w * f.y;
    }

    int beg = off[wid], end = off[wid + 1];
    int Em1 = E - 1;
    for (int j = beg; j < end; j += 4) {
        int i1 = j + 1, i2 = j + 2, i3 = j + 3;
        int s0 = csr_src[j];
        int s1 = csr_src[(i1 < E) ? i1 : Em1];
        int s2 = csr_src[(i2 < E) ? i2 : Em1];
        int s3 = csr_src[(i3 < E) ? i3 : Em1];
        uint v0 = hrows[(size_t)s0 * 64 + lane];
        uint v1 = hrows[(size_t)s1 * 64 + lane];
        uint v2 = hrows[(size_t)s2 * 64 + lane];
        uint v3 = hrows[(size_t)s3 * 64 + lane];
        float e0 = asrc[s0] + ad, e1 = asrc[s1] + ad;
        float e2 = asrc[s2] + ad, e3 = asrc[s3] + ad;
        e0 = (e0 > 0.f) ? e0 : NEG_SLOPE * e0; float w0 = __expf(e0);
        e1 = (e1 > 0.f) ? e1 : NEG_SLOPE * e1; float w1 = __expf(e1);
        e2 = (e2 > 0.f) ? e2 : NEG_SLOPE * e2; float w2 = __expf(e2);
        e3 = (e3 > 0.f) ? e3 : NEG_SLOPE * e3; float w3 = __expf(e3);
        w1 = (i1 < end) ? w1 : 0.f;
        w2 = (i2 < end) ? w2 : 0.f;
        w3 = (i3 < end) ? w3 : 0.f;
        denom += (w0 + w1) + (w2 + w3);
        float2 f0 = h2_to_f2(v0), f1 = h2_to_f2(v1);
        float2 f2 = h2_to_f2(v2), f3 = h2_to_f2(v3);
        acc0 += w0 * f0.x + w1 * f1.x + w2 * f2.x + w3 * f3.x;
        acc1 += w0 * f0.y + w1 * f1.y + w2 * f2.y + w3 * f3.y;
    }

    float inv = 1.0f / denom;
    float2 b2 = ((const float2*)bias)[lane];
    float o0 = acc0 * inv + b2.x;
    float o1 = acc1 * inv + b2.y;
    if (FINAL) {
        ((float2*)out_f)[(size_t)wid * 64 + lane] = make_float2(o0, o1);
    } else {
        o0 = (o0 > 0.f) ? o0 : (__expf(o0) - 1.0f);   // ELU
        o1 = (o1 > 0.f) ? o1 : (__expf(o1) - 1.0f);
        __bf16 h0 = (__bf16)o0, h1 = (__bf16)o1;
        bf16x2 ph = { h0, h1 };
        bf16x2 pl = { (__bf16)(o0 - (float)h0), (__bf16)(o1 - (float)h1) };
        ((bf16x2*)a_hi)[(size_t)wid * 64 + lane] = ph;
        ((bf16x2*)a_lo)[(size_t)wid * 64 + lane] = pl;
    }
}

// ============================ launch =====================================

extern "C" void kernel_launch(void* const* d_in, const int* in_sizes, int n_in,
                              void* d_out, int out_size, void* d_ws, size_t ws_size,
                              hipStream_t stream) {
    const float* x = (const float*)d_in[0];
    const int* ei = (const int*)d_in[1];
    int N = in_sizes[0] / 128;
    int E = in_sizes[1] / 2;
    const int* src = ei;
    const int* dst = ei + E;

    const float* Wl_[3] = { (const float*)d_in[2], (const float*)d_in[6], (const float*)d_in[10] };
    const float* asl[3] = { (const float*)d_in[3], (const float*)d_in[7], (const float*)d_in[11] };
    const float* adl[3] = { (const float*)d_in[4], (const float*)d_in[8], (const float*)d_in[12] };
    const float* bl[3]  = { (const float*)d_in[5], (const float*)d_in[9], (const float*)d_in[13] };

    // ---- workspace (~34 MB) ----
    size_t nfeat = (size_t)N * 128;
    char* p = (char*)d_ws;
    _Float16* Hh = (_Float16*)p; p += nfeat * 2;       // fp16 gather table
    __bf16* Wfh = (__bf16*)p; p += 3 * 16384 * 2;      // fragment-ordered W hi
    __bf16* Wfl = (__bf16*)p; p += 3 * 16384 * 2;      // fragment-ordered W lo
    float* asrc = (float*)p;  p += (size_t)N * 4;
    float* adst = (float*)p;  p += (size_t)N * 4;
    int* off    = (int*)p;    p += (size_t)(N + 1) * 4;
    int* cursor = (int*)p;    p += (size_t)N * 4;
    int* bsum   = (int*)p;    p += 4096 * 4;
    int* csr    = (int*)p;

    // activations ping-pong through d_out: hi then lo bf16 (= 51.2 MB total)
    __bf16* A_hi = (__bf16*)d_out;
    __bf16* A_lo = A_hi + nfeat;

    int G = (N + 1023) / 1024;

    // ---- CSR build (grouped by dst) ----
    hipMemsetAsync(cursor, 0, (size_t)N * sizeof(int), stream);
    count_deg<<<(E + 255) / 256, 256, 0, stream>>>(dst, cursor, E);
    scan_block_k<<<G, 256, 0, stream>>>(cursor, off, bsum, N);
    scan_bsum_k<<<1, 1024, 0, stream>>>(bsum, G);
    add_bsum_k<<<(N + 256) / 256, 256, 0, stream>>>(off, bsum, N, E);
    copy_off_k<<<(N + 255) / 256, 256, 0, stream>>>(off, cursor, N);
    fill_csr<<<(E + 255) / 256, 256, 0, stream>>>(src, dst, cursor, csr, E);

    // ---- splits ----
    split_w_k<<<dim3(64, 3), 256, 0, stream>>>(Wl_[0], Wl_[1], Wl_[2], Wfh, Wfl);
    int n4 = (int)(nfeat / 4);
    split_x_k<<<(n4 + 255) / 256, 256, 0, stream>>>(x, A_hi, A_lo, n4);

    int gemm_blocks = (N + 63) / 64;
    int wave_blocks = (N + 3) / 4;

    for (int l = 0; l < 3; ++l) {
        gemm_split<<<gemm_blocks, 256, 0, stream>>>(
            A_hi, A_lo, Wfh + (size_t)l * 16384, Wfl + (size_t)l * 16384,
            asl[l], adl[l], Hh, asrc, adst, N);
        if (l < 2) {
            aggregate_k<0><<<wave_blocks, 256, 0, stream>>>(
                Hh, asrc, adst, off, csr, bl[l], nullptr, A_hi, A_lo, N, E);
        } else {
            aggregate_k<1><<<wave_blocks, 256, 0, stream>>>(
                Hh, asrc, adst, off, csr, bl[l], (float*)d_out, nullptr, nullptr, N, E);
        }
    }
}

// Round 7
// 611.400 us; speedup vs baseline: 1.1016x; 1.1016x over previous
//
#include <hip/hip_runtime.h>
#include <hip/hip_bf16.h>
#include <hip/hip_fp16.h>
#include <math.h>

#define NEG_SLOPE 0.2f

typedef unsigned int uint;
typedef __bf16 bf16x8 __attribute__((ext_vector_type(8)));
typedef __bf16 bf16x4 __attribute__((ext_vector_type(4)));
typedef __bf16 bf16x2 __attribute__((ext_vector_type(2)));
typedef _Float16 f16x2 __attribute__((ext_vector_type(2)));
typedef float floatx4 __attribute__((ext_vector_type(4)));

__device__ inline float2 h2_to_f2(uint v) {
    f16x2 p = __builtin_bit_cast(f16x2, v);
    return make_float2((float)p[0], (float)p[1]);
}

// ============================ CSR build =================================

__global__ void count_deg(const int* __restrict__ dst, int* __restrict__ deg, int E) {
    int i = blockIdx.x * blockDim.x + threadIdx.x;
    if (i < E) atomicAdd(&deg[dst[i]], 1);
}

__global__ void scan_block_k(const int* __restrict__ deg, int* __restrict__ off,
                             int* __restrict__ bsum, int N) {
    __shared__ int sdata[256];
    int t = threadIdx.x;
    int base = blockIdx.x * 1024 + t * 4;
    int v0 = (base + 0 < N) ? deg[base + 0] : 0;
    int v1 = (base + 1 < N) ? deg[base + 1] : 0;
    int v2 = (base + 2 < N) ? deg[base + 2] : 0;
    int v3 = (base + 3 < N) ? deg[base + 3] : 0;
    int s = v0 + v1 + v2 + v3;
    sdata[t] = s;
    __syncthreads();
    for (int d = 1; d < 256; d <<= 1) {
        int x = (t >= d) ? sdata[t - d] : 0;
        __syncthreads();
        sdata[t] += x;
        __syncthreads();
    }
    int run = sdata[t] - s;  // exclusive prefix within block
    if (t == 255) bsum[blockIdx.x] = sdata[255];
    if (base + 0 < N) off[base + 0] = run; run += v0;
    if (base + 1 < N) off[base + 1] = run; run += v1;
    if (base + 2 < N) off[base + 2] = run; run += v2;
    if (base + 3 < N) off[base + 3] = run;
}

__global__ void scan_bsum_k(int* bsum, int G) {
    __shared__ int sdata[1024];
    int t = threadIdx.x;
    int v = (t < G) ? bsum[t] : 0;
    sdata[t] = v;
    __syncthreads();
    for (int d = 1; d < 1024; d <<= 1) {
        int x = (t >= d) ? sdata[t - d] : 0;
        __syncthreads();
        sdata[t] += x;
        __syncthreads();
    }
    if (t < G) bsum[t] = sdata[t] - v;  // exclusive
}

__global__ void add_bsum_k(int* __restrict__ off, const int* __restrict__ bsum,
                           int N, int Etot) {
    int i = blockIdx.x * blockDim.x + threadIdx.x;
    if (i < N) off[i] += bsum[i >> 10];
    else if (i == N) off[N] = Etot;
}

__global__ void copy_off_k(const int* __restrict__ off, int* __restrict__ cursor, int N) {
    int i = blockIdx.x * blockDim.x + threadIdx.x;
    if (i < N) cursor[i] = off[i];
}

// XCD-partitioned CSR scatter. part = blockIdx%8 owns dst range
// [part*nlo, part*nlo+nlo); its blocks grid-stride the WHOLE edge list and
// scatter only in-range edges. All writers of a CSR slice (~E/8*4B = 800KB)
// are heuristically on one XCD (blockIdx%8 round-robin), so the slice stays
// in that XCD's 4MiB L2 and partial-line stores MERGE before writeback.
// (Unpartitioned version measured 100-107MB WRITE_SIZE for 6.4MB payload:
// zero merging across 8 non-coherent L2s.) Correctness is independent of the
// XCD mapping — the range filter alone guarantees each edge scatters once.
__global__ void fill_csr_part(const int* __restrict__ src, const int* __restrict__ dst,
                              int* __restrict__ cursor, int* __restrict__ csr_src,
                              int E, int nlo) {
    int part = blockIdx.x & 7;
    int lo = part * nlo, hi = lo + nlo;
    int stride = (gridDim.x >> 3) * blockDim.x;
    for (int i = (blockIdx.x >> 3) * blockDim.x + threadIdx.x; i < E; i += stride) {
        int d = dst[i];
        if (d >= lo && d < hi) {
            int p = atomicAdd(&cursor[d], 1);
            csr_src[p] = src[i];
        }
    }
}

// ===================== splits (fp32 -> hi/lo bf16) =======================

__global__ void split_x_k(const float* __restrict__ in, __bf16* __restrict__ hi,
                          __bf16* __restrict__ lo, int n4) {
    int i = blockIdx.x * blockDim.x + threadIdx.x;
    if (i >= n4) return;
    float4 v = ((const float4*)in)[i];
    bf16x4 h = { (__bf16)v.x, (__bf16)v.y, (__bf16)v.z, (__bf16)v.w };
    bf16x4 l = { (__bf16)(v.x - (float)h[0]), (__bf16)(v.y - (float)h[1]),
                 (__bf16)(v.z - (float)h[2]), (__bf16)(v.w - (float)h[3]) };
    ((bf16x4*)hi)[i] = h;
    ((bf16x4*)lo)[i] = l;
}

// split + fragment-order all three 128x128 W's.
// Wf element (ct,kt,q,n16,j) holds W[k][ncol] with k = kt*32+q*8+j,
// ncol = ct*16+n16. Flat: (((ct*4+kt)*64) + q*16 + n16)*8 + j
// -> a wave's B-frag load (fixed ct,kt; lane = q*16+n16) is contiguous 1 KB.
__global__ void split_w_k(const float* __restrict__ W0, const float* __restrict__ W1,
                          const float* __restrict__ W2, __bf16* __restrict__ Wfh,
                          __bf16* __restrict__ Wfl) {
    const float* W = (blockIdx.y == 0) ? W0 : (blockIdx.y == 1) ? W1 : W2;
    size_t base = (size_t)blockIdx.y * 16384;
    int i = blockIdx.x * 256 + threadIdx.x;   // 0..16383
    int k = i >> 7, ncol = i & 127;
    int ct = ncol >> 4, n16 = ncol & 15;
    int kt = k >> 5, q = (k & 31) >> 3, j = k & 7;
    size_t flat = (size_t)(((ct * 4 + kt) * 64) + q * 16 + n16) * 8 + j;
    float v = W[i];
    __bf16 h = (__bf16)v;
    __bf16 l = (__bf16)(v - (float)h);
    Wfh[base + flat] = h;
    Wfl[base + flat] = l;
}

// ================ split-bf16 MFMA GEMM + fused alphas ====================
// h = Ah*Wh + Ah*Wl + Al*Wh  (fp32-equivalent, rel err ~2^-18).
// 256 threads = 4 waves; wave = 16-row strip x 128 cols,
// 8 col-tiles x 4 k-steps x 3 MFMAs. A frags from global (row-major bf16,
// 64B/row contiguous per load); B frags from fragment-ordered W tables
// (contiguous 1KB per wave-load, L2-resident). Epilogue: alphas from fp32
// acc (shfl_xor over n-lanes); fp16 H via LDS.

__global__ __launch_bounds__(256, 2) void gemm_split(
    const __bf16* __restrict__ Ah, const __bf16* __restrict__ Al,
    const __bf16* __restrict__ Wh, const __bf16* __restrict__ Wl,
    const float* __restrict__ avs, const float* __restrict__ avd,
    _Float16* __restrict__ Hh, float* __restrict__ asrc, float* __restrict__ adst,
    int M) {
    __shared__ _Float16 hl[64][132];
    int tid = threadIdx.x;
    int wv = tid >> 6, lane = tid & 63;
    int n = lane & 15, q = lane >> 4;

    int arow_g = blockIdx.x * 64 + wv * 16 + n;
    int arow_c = (arow_g < M) ? arow_g : (M - 1);
    const bf16x8* ah = (const bf16x8*)(Ah + (size_t)arow_c * 128);
    const bf16x8* al = (const bf16x8*)(Al + (size_t)arow_c * 128);
    bf16x8 a_h[4], a_l[4];
    #pragma unroll
    for (int kt = 0; kt < 4; ++kt) {
        a_h[kt] = ah[kt * 4 + q];   // k = kt*32 + q*8 + j
        a_l[kt] = al[kt * 4 + q];
    }

    floatx4 acc[8];
    #pragma unroll
    for (int ct = 0; ct < 8; ++ct) {
        floatx4 c = {0.f, 0.f, 0.f, 0.f};
        #pragma unroll
        for (int kt = 0; kt < 4; ++kt) {
            size_t fo = (size_t)((ct * 4 + kt) * 64 + lane);
            bf16x8 bh = ((const bf16x8*)Wh)[fo];
            bf16x8 bl = ((const bf16x8*)Wl)[fo];
            c = __builtin_amdgcn_mfma_f32_16x16x32_bf16(a_h[kt], bh, c, 0, 0, 0);
            c = __builtin_amdgcn_mfma_f32_16x16x32_bf16(a_h[kt], bl, c, 0, 0, 0);
            c = __builtin_amdgcn_mfma_f32_16x16x32_bf16(a_l[kt], bh, c, 0, 0, 0);
        }
        acc[ct] = c;
    }

    // fused alphas. D layout: row = q*4+r, col = ct*16+n.
    float ps[4] = {0.f, 0.f, 0.f, 0.f}, pd[4] = {0.f, 0.f, 0.f, 0.f};
    #pragma unroll
    for (int ct = 0; ct < 8; ++ct) {
        float sv = avs[ct * 16 + n], dv = avd[ct * 16 + n];
        #pragma unroll
        for (int r = 0; r < 4; ++r) {
            ps[r] += acc[ct][r] * sv;
            pd[r] += acc[ct][r] * dv;
        }
    }
    #pragma unroll
    for (int m = 1; m < 16; m <<= 1) {
        #pragma unroll
        for (int r = 0; r < 4; ++r) {
            ps[r] += __shfl_xor(ps[r], m, 64);
            pd[r] += __shfl_xor(pd[r], m, 64);
        }
    }
    if (n == 0) {
        #pragma unroll
        for (int r = 0; r < 4; ++r) {
            int grow = blockIdx.x * 64 + wv * 16 + q * 4 + r;
            if (grow < M) { asrc[grow] = ps[r]; adst[grow] = pd[r]; }
        }
    }

    // fp16 H store via LDS (coalesced uint)
    #pragma unroll
    for (int ct = 0; ct < 8; ++ct)
        #pragma unroll
        for (int r = 0; r < 4; ++r)
            hl[wv * 16 + q * 4 + r][ct * 16 + n] = (_Float16)acc[ct][r];
    __syncthreads();

    int r0 = blockIdx.x * 64;
    for (int i = tid; i < 64 * 64; i += 256) {
        int rr = i >> 6, cu = i & 63;
        int gr = r0 + rr;
        if (gr < M)
            ((uint*)Hh)[(size_t)gr * 64 + cu] = *(const uint*)&hl[rr][cu * 2];
    }
}

// ========================= edge aggregation ==============================
// one wave per dst node; fp16 h rows (256 B, one uint/lane). Edges in masked
// chunks of 4 -> 4 independent gather chains in flight per wave.
// Softmax weights are fp32-exact (alphas from exact GEMM accumulators);
// only the averaged features carry fp16 noise (~2^-11, non-compounding).

template <int FINAL>
__global__ __launch_bounds__(256) void aggregate_k(
    const _Float16* __restrict__ h, const float* __restrict__ asrc,
    const float* __restrict__ adst, const int* __restrict__ off,
    const int* __restrict__ csr_src, const float* __restrict__ bias,
    float* __restrict__ out_f, __bf16* __restrict__ a_hi, __bf16* __restrict__ a_lo,
    int N, int E) {
    int gid = blockIdx.x * blockDim.x + threadIdx.x;
    int wid = gid >> 6, lane = gid & 63;
    if (wid >= N) return;
    const uint* hrows = (const uint*)h;   // 64 uints (128 fp16) per row
    float ad = adst[wid];
    float acc0, acc1, denom;

    {   // self loop
        float e = asrc[wid] + ad;
        e = (e > 0.f) ? e : NEG_SLOPE * e;
        float w = __expf(e);
        float2 f = h2_to_f2(hrows[(size_t)wid * 64 + lane]);
        denom = w; acc0 = w * f.x; acc1 = w * f.y;
    }

    int beg = off[wid], end = off[wid + 1];
    int Em1 = E - 1;
    for (int j = beg; j < end; j += 4) {
        int i1 = j + 1, i2 = j + 2, i3 = j + 3;
        int s0 = csr_src[j];
        int s1 = csr_src[(i1 < E) ? i1 : Em1];
        int s2 = csr_src[(i2 < E) ? i2 : Em1];
        int s3 = csr_src[(i3 < E) ? i3 : Em1];
        uint v0 = hrows[(size_t)s0 * 64 + lane];
        uint v1 = hrows[(size_t)s1 * 64 + lane];
        uint v2 = hrows[(size_t)s2 * 64 + lane];
        uint v3 = hrows[(size_t)s3 * 64 + lane];
        float e0 = asrc[s0] + ad, e1 = asrc[s1] + ad;
        float e2 = asrc[s2] + ad, e3 = asrc[s3] + ad;
        e0 = (e0 > 0.f) ? e0 : NEG_SLOPE * e0; float w0 = __expf(e0);
        e1 = (e1 > 0.f) ? e1 : NEG_SLOPE * e1; float w1 = __expf(e1);
        e2 = (e2 > 0.f) ? e2 : NEG_SLOPE * e2; float w2 = __expf(e2);
        e3 = (e3 > 0.f) ? e3 : NEG_SLOPE * e3; float w3 = __expf(e3);
        w1 = (i1 < end) ? w1 : 0.f;
        w2 = (i2 < end) ? w2 : 0.f;
        w3 = (i3 < end) ? w3 : 0.f;
        denom += (w0 + w1) + (w2 + w3);
        float2 f0 = h2_to_f2(v0), f1 = h2_to_f2(v1);
        float2 f2 = h2_to_f2(v2), f3 = h2_to_f2(v3);
        acc0 += w0 * f0.x + w1 * f1.x + w2 * f2.x + w3 * f3.x;
        acc1 += w0 * f0.y + w1 * f1.y + w2 * f2.y + w3 * f3.y;
    }

    float inv = 1.0f / denom;
    float2 b2 = ((const float2*)bias)[lane];
    float o0 = acc0 * inv + b2.x;
    float o1 = acc1 * inv + b2.y;
    if (FINAL) {
        ((float2*)out_f)[(size_t)wid * 64 + lane] = make_float2(o0, o1);
    } else {
        o0 = (o0 > 0.f) ? o0 : (__expf(o0) - 1.0f);   // ELU
        o1 = (o1 > 0.f) ? o1 : (__expf(o1) - 1.0f);
        __bf16 h0 = (__bf16)o0, h1 = (__bf16)o1;
        bf16x2 ph = { h0, h1 };
        bf16x2 pl = { (__bf16)(o0 - (float)h0), (__bf16)(o1 - (float)h1) };
        ((bf16x2*)a_hi)[(size_t)wid * 64 + lane] = ph;
        ((bf16x2*)a_lo)[(size_t)wid * 64 + lane] = pl;
    }
}

// ============================ launch =====================================

extern "C" void kernel_launch(void* const* d_in, const int* in_sizes, int n_in,
                              void* d_out, int out_size, void* d_ws, size_t ws_size,
                              hipStream_t stream) {
    const float* x = (const float*)d_in[0];
    const int* ei = (const int*)d_in[1];
    int N = in_sizes[0] / 128;
    int E = in_sizes[1] / 2;
    const int* src = ei;
    const int* dst = ei + E;

    const float* Wl_[3] = { (const float*)d_in[2], (const float*)d_in[6], (const float*)d_in[10] };
    const float* asl[3] = { (const float*)d_in[3], (const float*)d_in[7], (const float*)d_in[11] };
    const float* adl[3] = { (const float*)d_in[4], (const float*)d_in[8], (const float*)d_in[12] };
    const float* bl[3]  = { (const float*)d_in[5], (const float*)d_in[9], (const float*)d_in[13] };

    // ---- workspace (~34 MB) ----
    size_t nfeat = (size_t)N * 128;
    char* p = (char*)d_ws;
    _Float16* Hh = (_Float16*)p; p += nfeat * 2;       // fp16 gather table
    __bf16* Wfh = (__bf16*)p; p += 3 * 16384 * 2;      // fragment-ordered W hi
    __bf16* Wfl = (__bf16*)p; p += 3 * 16384 * 2;      // fragment-ordered W lo
    float* asrc = (float*)p;  p += (size_t)N * 4;
    float* adst = (float*)p;  p += (size_t)N * 4;
    int* off    = (int*)p;    p += (size_t)(N + 1) * 4;
    int* cursor = (int*)p;    p += (size_t)N * 4;
    int* bsum   = (int*)p;    p += 4096 * 4;
    int* csr    = (int*)p;

    // activations ping-pong through d_out: hi then lo bf16 (= 51.2 MB total)
    __bf16* A_hi = (__bf16*)d_out;
    __bf16* A_lo = A_hi + nfeat;

    int G = (N + 1023) / 1024;

    // ---- CSR build (grouped by dst) ----
    hipMemsetAsync(cursor, 0, (size_t)N * sizeof(int), stream);
    count_deg<<<(E + 255) / 256, 256, 0, stream>>>(dst, cursor, E);
    scan_block_k<<<G, 256, 0, stream>>>(cursor, off, bsum, N);
    scan_bsum_k<<<1, 1024, 0, stream>>>(bsum, G);
    add_bsum_k<<<(N + 256) / 256, 256, 0, stream>>>(off, bsum, N, E);
    copy_off_k<<<(N + 255) / 256, 256, 0, stream>>>(off, cursor, N);
    int nlo = (N + 7) / 8;
    fill_csr_part<<<1024, 256, 0, stream>>>(src, dst, cursor, csr, E, nlo);

    // ---- splits ----
    split_w_k<<<dim3(64, 3), 256, 0, stream>>>(Wl_[0], Wl_[1], Wl_[2], Wfh, Wfl);
    int n4 = (int)(nfeat / 4);
    split_x_k<<<(n4 + 255) / 256, 256, 0, stream>>>(x, A_hi, A_lo, n4);

    int gemm_blocks = (N + 63) / 64;
    int wave_blocks = (N + 3) / 4;

    for (int l = 0; l < 3; ++l) {
        gemm_split<<<gemm_blocks, 256, 0, stream>>>(
            A_hi, A_lo, Wfh + (size_t)l * 16384, Wfl + (size_t)l * 16384,
            asl[l], adl[l], Hh, asrc, adst, N);
        if (l < 2) {
            aggregate_k<0><<<wave_blocks, 256, 0, stream>>>(
                Hh, asrc, adst, off, csr, bl[l], nullptr, A_hi, A_lo, N, E);
        } else {
            aggregate_k<1><<<wave_blocks, 256, 0, stream>>>(
                Hh, asrc, adst, off, csr, bl[l], (float*)d_out, nullptr, nullptr, N, E);
        }
    }
}